// Round 1
// baseline (791.277 us; speedup 1.0000x reference)
//
#include <hip/hip_runtime.h>

#define NN 100000
#define NE 1600000
// feature dims
#define NF 128
#define NH 256
#define NC 47

// ---------------- CSR build ----------------

__global__ void count_deg_k(const int* __restrict__ dst, int* __restrict__ deg) {
    int e = blockIdx.x * blockDim.x + threadIdx.x;
    if (e < NE) atomicAdd(&deg[dst[e]], 1);
}

__global__ __launch_bounds__(1024) void scan_block_k(const int* __restrict__ deg,
                                                     int* __restrict__ row_start,
                                                     int* __restrict__ bsum) {
    __shared__ int s[1024];
    int tid = threadIdx.x;
    int i = blockIdx.x * 1024 + tid;
    int v = (i < NN) ? deg[i] : 0;
    s[tid] = v;
    __syncthreads();
    for (int off = 1; off < 1024; off <<= 1) {
        int t = (tid >= off) ? s[tid - off] : 0;
        __syncthreads();
        s[tid] += t;
        __syncthreads();
    }
    if (i < NN) row_start[i] = s[tid] - v;   // exclusive within block
    if (tid == 1023) bsum[blockIdx.x] = s[1023];
}

__global__ void scan_bsum_k(int* __restrict__ bsum, int nb) {
    __shared__ int s[128];
    int tid = threadIdx.x;
    int v = (tid < nb) ? bsum[tid] : 0;
    s[tid] = v;
    __syncthreads();
    for (int off = 1; off < 128; off <<= 1) {
        int t = (tid >= off) ? s[tid - off] : 0;
        __syncthreads();
        s[tid] += t;
        __syncthreads();
    }
    if (tid < nb) bsum[tid] = s[tid] - v;    // exclusive block offsets, in place
}

__global__ __launch_bounds__(1024) void scan_add_k(int* __restrict__ row_start,
                                                   int* __restrict__ row_pos,
                                                   float* __restrict__ inv_deg,
                                                   const int* __restrict__ deg,
                                                   const int* __restrict__ bsum) {
    int i = blockIdx.x * 1024 + threadIdx.x;
    if (i < NN) {
        int rs = row_start[i] + bsum[blockIdx.x];
        row_start[i] = rs;
        row_pos[i] = rs;
        int d = deg[i];
        inv_deg[i] = 1.0f / (float)(d > 1 ? d : 1);
    }
}

__global__ void fill_csr_k(const int* __restrict__ src, const int* __restrict__ dst,
                           int* __restrict__ row_pos, int* __restrict__ csr_src) {
    int e = blockIdx.x * blockDim.x + threadIdx.x;
    if (e < NE) {
        int p = atomicAdd(&row_pos[dst[e]], 1);
        csr_src[p] = src[e];
    }
}

// ---------------- aggregation: wave per node ----------------

// mean1[i,:] = (1/max(deg,1)) * sum_{j in nbrs(i)} x[j,:]   (128 f32: float2/lane)
__global__ __launch_bounds__(256) void agg_mean_128_k(const float* __restrict__ x,
                                                      const int* __restrict__ csr_src,
                                                      const int* __restrict__ row_start,
                                                      const int* __restrict__ deg,
                                                      const float* __restrict__ inv_deg,
                                                      float* __restrict__ mean1) {
    int node = (blockIdx.x * 256 + threadIdx.x) >> 6;
    int lane = threadIdx.x & 63;
    if (node >= NN) return;
    int s0 = row_start[node];
    int d  = deg[node];
    float ax = 0.f, ay = 0.f;
    for (int j = 0; j < d; ++j) {
        int s = csr_src[s0 + j];
        float2 v = *reinterpret_cast<const float2*>(x + (size_t)s * NF + lane * 2);
        ax += v.x; ay += v.y;
    }
    float inv = inv_deg[node];
    float2 o; o.x = ax * inv; o.y = ay * inv;
    *reinterpret_cast<float2*>(mean1 + (size_t)node * NF + lane * 2) = o;
}

// out[i,c] += (1/max(deg,1)) * sum_{j in nbrs(i)} t[j,c]   (47 f32, lanes 0..46)
__global__ __launch_bounds__(256) void agg_mean_47_add_k(const float* __restrict__ t,
                                                         const int* __restrict__ csr_src,
                                                         const int* __restrict__ row_start,
                                                         const int* __restrict__ deg,
                                                         const float* __restrict__ inv_deg,
                                                         float* __restrict__ out) {
    int node = (blockIdx.x * 256 + threadIdx.x) >> 6;
    int lane = threadIdx.x & 63;
    if (node >= NN) return;
    int s0 = row_start[node];
    int d  = deg[node];
    float acc = 0.f;
    for (int j = 0; j < d; ++j) {
        int s = csr_src[s0 + j];
        if (lane < NC) acc += t[(size_t)s * NC + lane];
    }
    if (lane < NC) {
        size_t o = (size_t)node * NC + lane;
        out[o] = out[o] + acc * inv_deg[node];
    }
}

// ---------------- GEMM1: h = relu([mean1 | x] @ [Wl1 ; Wr1] + b1) ----------------
// M=100000, K=256 (two 128 halves), N=256. BM=64, BN=64, BK=32, 256 thr, 4x4/thr.

__global__ __launch_bounds__(256) void gemm1_k(const float* __restrict__ mean1,
                                               const float* __restrict__ x,
                                               const float* __restrict__ Wl1,
                                               const float* __restrict__ Wr1,
                                               const float* __restrict__ b1,
                                               float* __restrict__ h) {
    __shared__ float As[64][36];   // 16B-aligned rows (144B stride)
    __shared__ float Bs[32][68];   // 272B stride
    int row0 = blockIdx.x * 64;
    int col0 = blockIdx.y * 64;
    int tid = threadIdx.x;
    int tx = tid & 15, ty = tid >> 4;
    float acc[4][4] = {};

    for (int kt = 0; kt < 256; kt += 32) {
        const float* Asrc = (kt < 128) ? mean1 : x;
        int kbase = (kt < 128) ? kt : (kt - 128);
        #pragma unroll
        for (int it = 0; it < 2; ++it) {
            int idx = it * 256 + tid;          // 0..511
            int r = idx >> 3;
            int c = (idx & 7) * 4;
            int row = row0 + r;
            float4 v = make_float4(0.f, 0.f, 0.f, 0.f);
            if (row < NN) v = *reinterpret_cast<const float4*>(Asrc + (size_t)row * NF + kbase + c);
            *reinterpret_cast<float4*>(&As[r][c]) = v;
        }
        #pragma unroll
        for (int it = 0; it < 2; ++it) {
            int idx = it * 256 + tid;          // 0..511
            int r = idx >> 4;                  // 0..31
            int c = (idx & 15) * 4;
            int kg = kt + r;
            const float* Bsrc = (kg < 128) ? (Wl1 + (size_t)kg * NH) : (Wr1 + (size_t)(kg - 128) * NH);
            float4 v = *reinterpret_cast<const float4*>(Bsrc + col0 + c);
            *reinterpret_cast<float4*>(&Bs[r][c]) = v;
        }
        __syncthreads();
        #pragma unroll
        for (int kk = 0; kk < 32; ++kk) {
            float4 bv = *reinterpret_cast<const float4*>(&Bs[kk][tx * 4]);
            float a0 = As[ty * 4 + 0][kk];
            float a1 = As[ty * 4 + 1][kk];
            float a2 = As[ty * 4 + 2][kk];
            float a3 = As[ty * 4 + 3][kk];
            acc[0][0] += a0 * bv.x; acc[0][1] += a0 * bv.y; acc[0][2] += a0 * bv.z; acc[0][3] += a0 * bv.w;
            acc[1][0] += a1 * bv.x; acc[1][1] += a1 * bv.y; acc[1][2] += a1 * bv.z; acc[1][3] += a1 * bv.w;
            acc[2][0] += a2 * bv.x; acc[2][1] += a2 * bv.y; acc[2][2] += a2 * bv.z; acc[2][3] += a2 * bv.w;
            acc[3][0] += a3 * bv.x; acc[3][1] += a3 * bv.y; acc[3][2] += a3 * bv.z; acc[3][3] += a3 * bv.w;
        }
        __syncthreads();
    }

    float4 bias = *reinterpret_cast<const float4*>(b1 + col0 + tx * 4);
    #pragma unroll
    for (int i = 0; i < 4; ++i) {
        int row = row0 + ty * 4 + i;
        if (row < NN) {
            float4 o;
            o.x = fmaxf(acc[i][0] + bias.x, 0.f);
            o.y = fmaxf(acc[i][1] + bias.y, 0.f);
            o.z = fmaxf(acc[i][2] + bias.z, 0.f);
            o.w = fmaxf(acc[i][3] + bias.w, 0.f);
            *reinterpret_cast<float4*>(h + (size_t)row * NH + col0 + tx * 4) = o;
        }
    }
}

// ---------------- Bcat2 prep: [256][96] = [Wl2 | pad | Wr2 | pad] ----------------

__global__ void prep_bcat2_k(const float* __restrict__ Wl2, const float* __restrict__ Wr2,
                             float* __restrict__ bcat) {
    int idx = blockIdx.x * 256 + threadIdx.x;
    if (idx >= 256 * 96) return;
    int k = idx / 96, j = idx % 96;
    float v = 0.f;
    if (j < 47) v = Wl2[(size_t)k * NC + j];
    else if (j >= 48 && j < 95) v = Wr2[(size_t)k * NC + (j - 48)];
    bcat[idx] = v;
}

// ---------------- GEMM2: t = h@Wl2 ; out = h@Wr2 + b2 ----------------
// M=100000, K=256, N=96 (48+48 fused). BM=64, BN=96, BK=32, 256 thr, 4x6/thr.

__global__ __launch_bounds__(256) void gemm2_k(const float* __restrict__ h,
                                               const float* __restrict__ bcat,
                                               const float* __restrict__ b2,
                                               float* __restrict__ t,
                                               float* __restrict__ out) {
    __shared__ float As[64][36];
    __shared__ float Bs[32][100];
    int row0 = blockIdx.x * 64;
    int tid = threadIdx.x;
    int tx = tid & 15, ty = tid >> 4;
    float acc[4][6] = {};

    for (int kt = 0; kt < 256; kt += 32) {
        #pragma unroll
        for (int it = 0; it < 2; ++it) {
            int idx = it * 256 + tid;
            int r = idx >> 3;
            int c = (idx & 7) * 4;
            int row = row0 + r;
            float4 v = make_float4(0.f, 0.f, 0.f, 0.f);
            if (row < NN) v = *reinterpret_cast<const float4*>(h + (size_t)row * NH + kt + c);
            *reinterpret_cast<float4*>(&As[r][c]) = v;
        }
        #pragma unroll
        for (int it = 0; it < 3; ++it) {
            int idx = it * 256 + tid;          // 0..767
            int r = idx / 24;                  // 0..31
            int c = (idx % 24) * 4;            // 0..92
            float4 v = *reinterpret_cast<const float4*>(bcat + (size_t)(kt + r) * 96 + c);
            *reinterpret_cast<float4*>(&Bs[r][c]) = v;
        }
        __syncthreads();
        #pragma unroll
        for (int kk = 0; kk < 32; ++kk) {
            float2 b0 = *reinterpret_cast<const float2*>(&Bs[kk][tx * 6 + 0]);
            float2 b1v = *reinterpret_cast<const float2*>(&Bs[kk][tx * 6 + 2]);
            float2 b2v = *reinterpret_cast<const float2*>(&Bs[kk][tx * 6 + 4]);
            float bb[6] = {b0.x, b0.y, b1v.x, b1v.y, b2v.x, b2v.y};
            float a[4];
            #pragma unroll
            for (int i = 0; i < 4; ++i) a[i] = As[ty * 4 + i][kk];
            #pragma unroll
            for (int i = 0; i < 4; ++i)
                #pragma unroll
                for (int j = 0; j < 6; ++j)
                    acc[i][j] += a[i] * bb[j];
        }
        __syncthreads();
    }

    #pragma unroll
    for (int i = 0; i < 4; ++i) {
        int row = row0 + ty * 4 + i;
        if (row < NN) {
            #pragma unroll
            for (int j = 0; j < 6; ++j) {
                int col = tx * 6 + j;
                float v = acc[i][j];
                if (col < 47) {
                    t[(size_t)row * NC + col] = v;
                } else if (col >= 48 && col < 95) {
                    int c2 = col - 48;
                    out[(size_t)row * NC + c2] = v + b2[c2];
                }
            }
        }
    }
}

// ---------------- launch ----------------

extern "C" void kernel_launch(void* const* d_in, const int* in_sizes, int n_in,
                              void* d_out, int out_size, void* d_ws, size_t ws_size,
                              hipStream_t stream) {
    const float* x    = (const float*)d_in[0];
    const int*   eidx = (const int*)d_in[1];     // [2][NE] row-major
    const float* Wl1  = (const float*)d_in[2];
    const float* Wr1  = (const float*)d_in[3];
    const float* b1   = (const float*)d_in[4];
    const float* Wl2  = (const float*)d_in[5];
    const float* Wr2  = (const float*)d_in[6];
    const float* b2   = (const float*)d_in[7];
    float* out = (float*)d_out;

    const int* src = eidx;
    const int* dst = eidx + NE;

    size_t off = 0;
    auto alloc = [&](size_t bytes) -> void* {
        void* p = (char*)d_ws + off;
        off += (bytes + 511) & ~(size_t)511;
        return p;
    };
    int*   deg       = (int*)alloc((size_t)NN * 4);
    int*   row_start = (int*)alloc((size_t)(NN + 1) * 4);
    int*   row_pos   = (int*)alloc((size_t)NN * 4);
    int*   bsum      = (int*)alloc(128 * 4);
    int*   csr_src   = (int*)alloc((size_t)NE * 4);
    float* inv_deg   = (float*)alloc((size_t)NN * 4);
    float* mean1     = (float*)alloc((size_t)NN * NF * 4);
    float* h         = (float*)alloc((size_t)NN * NH * 4);
    float* t         = (float*)alloc((size_t)NN * NC * 4);
    float* bcat2     = (float*)alloc((size_t)256 * 96 * 4);
    (void)ws_size; (void)n_in; (void)in_sizes; (void)out_size;

    const int nscan = (NN + 1023) / 1024;   // 98

    hipMemsetAsync(deg, 0, (size_t)NN * 4, stream);
    count_deg_k<<<(NE + 255) / 256, 256, 0, stream>>>(dst, deg);
    scan_block_k<<<nscan, 1024, 0, stream>>>(deg, row_start, bsum);
    scan_bsum_k<<<1, 128, 0, stream>>>(bsum, nscan);
    scan_add_k<<<nscan, 1024, 0, stream>>>(row_start, row_pos, inv_deg, deg, bsum);
    fill_csr_k<<<(NE + 255) / 256, 256, 0, stream>>>(src, dst, row_pos, csr_src);

    agg_mean_128_k<<<NN / 4, 256, 0, stream>>>(x, csr_src, row_start, deg, inv_deg, mean1);

    prep_bcat2_k<<<(256 * 96 + 255) / 256, 256, 0, stream>>>(Wl2, Wr2, bcat2);

    gemm1_k<<<dim3((NN + 63) / 64, 4), 256, 0, stream>>>(mean1, x, Wl1, Wr1, b1, h);
    gemm2_k<<<(NN + 63) / 64, 256, 0, stream>>>(h, bcat2, b2, t, out);

    agg_mean_47_add_k<<<NN / 4, 256, 0, stream>>>(t, csr_src, row_start, deg, inv_deg, out);
}

// Round 2
// 615.068 us; speedup vs baseline: 1.2865x; 1.2865x over previous
//
#include <hip/hip_runtime.h>

#define NN 100000
#define NE 1600000
#define NF 128
#define NH 256
#define NC 47

typedef __attribute__((ext_vector_type(8))) short bf16x8;
typedef __attribute__((ext_vector_type(4))) float f32x4;

__device__ inline unsigned short f2bf(float f) {
    unsigned u = __builtin_bit_cast(unsigned, f);
    unsigned r = u + 0x7fffu + ((u >> 16) & 1u);
    return (unsigned short)(r >> 16);
}
__device__ inline float bfl(unsigned u) {           // low ushort -> float
    return __builtin_bit_cast(float, u << 16);
}
__device__ inline float bfh(unsigned u) {           // high ushort -> float
    return __builtin_bit_cast(float, u & 0xffff0000u);
}

// ---------------- CSR build ----------------

__global__ void count_deg_k(const int* __restrict__ dst, int* __restrict__ deg) {
    int e = blockIdx.x * blockDim.x + threadIdx.x;
    if (e < NE) atomicAdd(&deg[dst[e]], 1);
}

__global__ __launch_bounds__(1024) void scan_block_k(const int* __restrict__ deg,
                                                     int* __restrict__ row_start,
                                                     int* __restrict__ bsum) {
    __shared__ int s[1024];
    int tid = threadIdx.x;
    int i = blockIdx.x * 1024 + tid;
    int v = (i < NN) ? deg[i] : 0;
    s[tid] = v;
    __syncthreads();
    for (int off = 1; off < 1024; off <<= 1) {
        int t = (tid >= off) ? s[tid - off] : 0;
        __syncthreads();
        s[tid] += t;
        __syncthreads();
    }
    if (i < NN) row_start[i] = s[tid] - v;
    if (tid == 1023) bsum[blockIdx.x] = s[1023];
}

__global__ void scan_bsum_k(int* __restrict__ bsum, int nb) {
    __shared__ int s[128];
    int tid = threadIdx.x;
    int v = (tid < nb) ? bsum[tid] : 0;
    s[tid] = v;
    __syncthreads();
    for (int off = 1; off < 128; off <<= 1) {
        int t = (tid >= off) ? s[tid - off] : 0;
        __syncthreads();
        s[tid] += t;
        __syncthreads();
    }
    if (tid < nb) bsum[tid] = s[tid] - v;
}

__global__ __launch_bounds__(1024) void scan_add_k(int* __restrict__ row_start,
                                                   int* __restrict__ row_pos,
                                                   float* __restrict__ inv_deg,
                                                   const int* __restrict__ deg,
                                                   const int* __restrict__ bsum) {
    int i = blockIdx.x * 1024 + threadIdx.x;
    if (i < NN) {
        int rs = row_start[i] + bsum[blockIdx.x];
        row_start[i] = rs;
        row_pos[i] = rs;
        int d = deg[i];
        inv_deg[i] = 1.0f / (float)(d > 1 ? d : 1);
    }
}

__global__ void fill_csr_k(const int* __restrict__ src, const int* __restrict__ dst,
                           int* __restrict__ row_pos, int* __restrict__ csr_src) {
    int e = blockIdx.x * blockDim.x + threadIdx.x;
    if (e < NE) {
        int p = atomicAdd(&row_pos[dst[e]], 1);
        csr_src[p] = src[e];
    }
}

// ---------------- dtype prep ----------------

__global__ void cast_x_k(const float* __restrict__ x, unsigned short* __restrict__ xb) {
    int i = blockIdx.x * 256 + threadIdx.x;        // 4 floats per thread
    if (i >= NN * NF / 4) return;
    float4 v = *reinterpret_cast<const float4*>(x + (size_t)i * 4);
    ushort4 o;
    o.x = f2bf(v.x); o.y = f2bf(v.y); o.z = f2bf(v.z); o.w = f2bf(v.w);
    *reinterpret_cast<ushort4*>(xb + (size_t)i * 4) = o;
}

// Bt1[n][k], n<256, k<256: k<128 -> Wl1[k][n], else Wr1[k-128][n]
__global__ void prep_bt1_k(const float* __restrict__ Wl1, const float* __restrict__ Wr1,
                           unsigned short* __restrict__ Bt1) {
    int idx = blockIdx.x * 256 + threadIdx.x;
    if (idx >= 256 * 256) return;
    int n = idx >> 8, k = idx & 255;
    float v = (k < 128) ? Wl1[(size_t)k * NH + n] : Wr1[(size_t)(k - 128) * NH + n];
    Bt1[idx] = f2bf(v);
}

// Bt2[n][k], n<96, k<256: n<47 -> Wl2[k][n]; 48<=n<95 -> Wr2[k][n-48]; else 0
__global__ void prep_bt2_k(const float* __restrict__ Wl2, const float* __restrict__ Wr2,
                           unsigned short* __restrict__ Bt2) {
    int idx = blockIdx.x * 256 + threadIdx.x;
    if (idx >= 96 * 256) return;
    int n = idx >> 8, k = idx & 255;
    float v = 0.f;
    if (n < 47) v = Wl2[(size_t)k * NC + n];
    else if (n >= 48 && n < 95) v = Wr2[(size_t)k * NC + (n - 48)];
    Bt2[idx] = f2bf(v);
}

// ---------------- aggregation ----------------

// mean1[i,:] = inv_deg * sum_{j->i} xb[j,:]  (bf16 in, f32 acc, bf16 out)
__global__ __launch_bounds__(256) void agg_mean_128b_k(const unsigned short* __restrict__ xb,
                                                       const int* __restrict__ csr_src,
                                                       const int* __restrict__ row_start,
                                                       const int* __restrict__ deg,
                                                       const float* __restrict__ inv_deg,
                                                       unsigned short* __restrict__ mean1) {
    int node = (blockIdx.x * 256 + threadIdx.x) >> 6;
    int lane = threadIdx.x & 63;
    if (node >= NN) return;
    int s0 = row_start[node];
    int d  = deg[node];
    float ax = 0.f, ay = 0.f;
    for (int j = 0; j < d; ++j) {
        int s = csr_src[s0 + j];
        unsigned u = *reinterpret_cast<const unsigned*>(xb + (size_t)s * NF + lane * 2);
        ax += bfl(u); ay += bfh(u);
    }
    float inv = inv_deg[node];
    unsigned o = (unsigned)f2bf(ax * inv) | ((unsigned)f2bf(ay * inv) << 16);
    *reinterpret_cast<unsigned*>(mean1 + (size_t)node * NF + lane * 2) = o;
}

// out[i,c] += inv_deg * sum_{j->i} t[j,c]   (47 f32, lanes 0..46)
__global__ __launch_bounds__(256) void agg_mean_47_add_k(const float* __restrict__ t,
                                                         const int* __restrict__ csr_src,
                                                         const int* __restrict__ row_start,
                                                         const int* __restrict__ deg,
                                                         const float* __restrict__ inv_deg,
                                                         float* __restrict__ out) {
    int node = (blockIdx.x * 256 + threadIdx.x) >> 6;
    int lane = threadIdx.x & 63;
    if (node >= NN) return;
    int s0 = row_start[node];
    int d  = deg[node];
    float acc = 0.f;
    for (int j = 0; j < d; ++j) {
        int s = csr_src[s0 + j];
        if (lane < NC) acc += t[(size_t)s * NC + lane];
    }
    if (lane < NC) {
        size_t o = (size_t)node * NC + lane;
        out[o] = out[o] + acc * inv_deg[node];
    }
}

// ---------------- GEMM1 (MFMA): h = relu([mean1|x]_bf16 @ Bt1^T + b1) ----------------
// M=100000, K=256, N=256. BM=128, BN=128, BK=32. 256 thr = 4 waves (2x2), 64x64/wave.

__global__ __launch_bounds__(256) void gemm1_mfma_k(const unsigned short* __restrict__ mean1,
                                                    const unsigned short* __restrict__ xb,
                                                    const unsigned short* __restrict__ Bt1,
                                                    const float* __restrict__ b1,
                                                    unsigned short* __restrict__ h) {
    __shared__ short As[2][128 * 32];
    __shared__ short Bs[2][128 * 32];
    const int tid = threadIdx.x;
    const int row0 = blockIdx.x * 128;
    const int col0 = blockIdx.y * 128;
    const int lane = tid & 63;
    const int wid = tid >> 6;
    const int wr = wid >> 1, wc = wid & 1;
    const int r15 = lane & 15;
    const int swz = ((lane >> 4) ^ ((lane >> 1) & 3)) & 3;

    f32x4 acc[4][4];
    #pragma unroll
    for (int i = 0; i < 4; ++i)
        #pragma unroll
        for (int j = 0; j < 4; ++j)
            acc[i][j] = f32x4{0.f, 0.f, 0.f, 0.f};

    bf16x8 ra[2], rb[2];

    auto load_tiles = [&](int kt) {
        #pragma unroll
        for (int i = 0; i < 2; ++i) {
            int c = tid + i * 256;
            int row = c >> 2, g = c & 3;
            // A
            int grow = row0 + row;
            const unsigned short* asrc = (kt < 128) ? mean1 : xb;
            int kb = (kt & 127) + g * 8;
            bf16x8 va = {0,0,0,0,0,0,0,0};
            if (grow < NN) va = *reinterpret_cast<const bf16x8*>(asrc + (size_t)grow * NF + kb);
            ra[i] = va;
            // B
            int n = col0 + row;
            rb[i] = *reinterpret_cast<const bf16x8*>(Bt1 + (size_t)n * 256 + kt + g * 8);
        }
    };
    auto write_tiles = [&](int buf) {
        #pragma unroll
        for (int i = 0; i < 2; ++i) {
            int c = tid + i * 256;
            int row = c >> 2, g = c & 3;
            int slot = g ^ ((row >> 1) & 3);
            *reinterpret_cast<bf16x8*>(&As[buf][row * 32 + slot * 8]) = ra[i];
            *reinterpret_cast<bf16x8*>(&Bs[buf][row * 32 + slot * 8]) = rb[i];
        }
    };
    auto compute = [&](int buf) {
        bf16x8 a[4], b[4];
        #pragma unroll
        for (int mi = 0; mi < 4; ++mi)
            a[mi] = *reinterpret_cast<const bf16x8*>(&As[buf][(wr * 64 + mi * 16 + r15) * 32 + swz * 8]);
        #pragma unroll
        for (int ni = 0; ni < 4; ++ni)
            b[ni] = *reinterpret_cast<const bf16x8*>(&Bs[buf][(wc * 64 + ni * 16 + r15) * 32 + swz * 8]);
        #pragma unroll
        for (int mi = 0; mi < 4; ++mi)
            #pragma unroll
            for (int ni = 0; ni < 4; ++ni)
                acc[mi][ni] = __builtin_amdgcn_mfma_f32_16x16x32_bf16(a[mi], b[ni], acc[mi][ni], 0, 0, 0);
    };

    load_tiles(0);
    write_tiles(0);
    __syncthreads();
    int cur = 0;
    #pragma unroll 1
    for (int ks = 0; ks < 8; ++ks) {
        if (ks + 1 < 8) load_tiles((ks + 1) * 32);
        compute(cur);
        if (ks + 1 < 8) write_tiles(cur ^ 1);
        __syncthreads();
        cur ^= 1;
    }

    #pragma unroll
    for (int ni = 0; ni < 4; ++ni) {
        int col = col0 + wc * 64 + ni * 16 + r15;
        float bias = b1[col];
        #pragma unroll
        for (int mi = 0; mi < 4; ++mi) {
            int rbase = row0 + wr * 64 + mi * 16 + (lane >> 4) * 4;
            f32x4 c = acc[mi][ni];
            #pragma unroll
            for (int q = 0; q < 4; ++q) {
                int row = rbase + q;
                if (row < NN) {
                    float v = fmaxf(c[q] + bias, 0.f);
                    h[(size_t)row * NH + col] = f2bf(v);
                }
            }
        }
    }
}

// ---------------- GEMM2 (MFMA): t = h@Wl2 ; out = h@Wr2 + b2 ----------------
// M=100000, K=256, N=96 (cols 0..46 -> t, 48..94 -> out). BM=128, BN=96, wave 64x48.

__global__ __launch_bounds__(256) void gemm2_mfma_k(const unsigned short* __restrict__ h,
                                                    const unsigned short* __restrict__ Bt2,
                                                    const float* __restrict__ b2,
                                                    float* __restrict__ t,
                                                    float* __restrict__ out) {
    __shared__ short As[2][128 * 32];
    __shared__ short Bs[2][96 * 32];
    const int tid = threadIdx.x;
    const int row0 = blockIdx.x * 128;
    const int lane = tid & 63;
    const int wid = tid >> 6;
    const int wr = wid >> 1, wc = wid & 1;
    const int r15 = lane & 15;
    const int swz = ((lane >> 4) ^ ((lane >> 1) & 3)) & 3;

    f32x4 acc[4][3];
    #pragma unroll
    for (int i = 0; i < 4; ++i)
        #pragma unroll
        for (int j = 0; j < 3; ++j)
            acc[i][j] = f32x4{0.f, 0.f, 0.f, 0.f};

    bf16x8 ra[2], rb[2];

    auto load_tiles = [&](int kt) {
        #pragma unroll
        for (int i = 0; i < 2; ++i) {
            int c = tid + i * 256;
            int row = c >> 2, g = c & 3;
            int grow = row0 + row;
            bf16x8 va = {0,0,0,0,0,0,0,0};
            if (grow < NN) va = *reinterpret_cast<const bf16x8*>(h + (size_t)grow * NH + kt + g * 8);
            ra[i] = va;
            if (c < 96 * 4)
                rb[i] = *reinterpret_cast<const bf16x8*>(Bt2 + (size_t)row * 256 + kt + g * 8);
        }
    };
    auto write_tiles = [&](int buf) {
        #pragma unroll
        for (int i = 0; i < 2; ++i) {
            int c = tid + i * 256;
            int row = c >> 2, g = c & 3;
            int slot = g ^ ((row >> 1) & 3);
            *reinterpret_cast<bf16x8*>(&As[buf][row * 32 + slot * 8]) = ra[i];
            if (c < 96 * 4)
                *reinterpret_cast<bf16x8*>(&Bs[buf][row * 32 + slot * 8]) = rb[i];
        }
    };
    auto compute = [&](int buf) {
        bf16x8 a[4], b[3];
        #pragma unroll
        for (int mi = 0; mi < 4; ++mi)
            a[mi] = *reinterpret_cast<const bf16x8*>(&As[buf][(wr * 64 + mi * 16 + r15) * 32 + swz * 8]);
        #pragma unroll
        for (int ni = 0; ni < 3; ++ni)
            b[ni] = *reinterpret_cast<const bf16x8*>(&Bs[buf][(wc * 48 + ni * 16 + r15) * 32 + swz * 8]);
        #pragma unroll
        for (int mi = 0; mi < 4; ++mi)
            #pragma unroll
            for (int ni = 0; ni < 3; ++ni)
                acc[mi][ni] = __builtin_amdgcn_mfma_f32_16x16x32_bf16(a[mi], b[ni], acc[mi][ni], 0, 0, 0);
    };

    load_tiles(0);
    write_tiles(0);
    __syncthreads();
    int cur = 0;
    #pragma unroll 1
    for (int ks = 0; ks < 8; ++ks) {
        if (ks + 1 < 8) load_tiles((ks + 1) * 32);
        compute(cur);
        if (ks + 1 < 8) write_tiles(cur ^ 1);
        __syncthreads();
        cur ^= 1;
    }

    #pragma unroll
    for (int ni = 0; ni < 3; ++ni) {
        int col = wc * 48 + ni * 16 + r15;       // 0..95
        float bias = (col >= 48 && col < 95) ? b2[col - 48] : 0.f;
        #pragma unroll
        for (int mi = 0; mi < 4; ++mi) {
            int rbase = row0 + wr * 64 + mi * 16 + (lane >> 4) * 4;
            f32x4 c = acc[mi][ni];
            #pragma unroll
            for (int q = 0; q < 4; ++q) {
                int row = rbase + q;
                if (row < NN) {
                    if (col < 47)
                        t[(size_t)row * NC + col] = c[q];
                    else if (col >= 48 && col < 95)
                        out[(size_t)row * NC + (col - 48)] = c[q] + bias;
                }
            }
        }
    }
}

// ---------------- launch ----------------

extern "C" void kernel_launch(void* const* d_in, const int* in_sizes, int n_in,
                              void* d_out, int out_size, void* d_ws, size_t ws_size,
                              hipStream_t stream) {
    const float* x    = (const float*)d_in[0];
    const int*   eidx = (const int*)d_in[1];
    const float* Wl1  = (const float*)d_in[2];
    const float* Wr1  = (const float*)d_in[3];
    const float* b1   = (const float*)d_in[4];
    const float* Wl2  = (const float*)d_in[5];
    const float* Wr2  = (const float*)d_in[6];
    const float* b2   = (const float*)d_in[7];
    float* out = (float*)d_out;

    const int* src = eidx;
    const int* dst = eidx + NE;

    size_t off = 0;
    auto alloc = [&](size_t bytes) -> void* {
        void* p = (char*)d_ws + off;
        off += (bytes + 511) & ~(size_t)511;
        return p;
    };
    int*            deg       = (int*)alloc((size_t)NN * 4);
    int*            row_start = (int*)alloc((size_t)(NN + 1) * 4);
    int*            row_pos   = (int*)alloc((size_t)NN * 4);
    int*            bsum      = (int*)alloc(128 * 4);
    int*            csr_src   = (int*)alloc((size_t)NE * 4);
    float*          inv_deg   = (float*)alloc((size_t)NN * 4);
    unsigned short* xb        = (unsigned short*)alloc((size_t)NN * NF * 2);
    unsigned short* mean1     = (unsigned short*)alloc((size_t)NN * NF * 2);
    unsigned short* hbuf      = (unsigned short*)alloc((size_t)NN * NH * 2);
    float*          t         = (float*)alloc((size_t)NN * NC * 4);
    unsigned short* Bt1       = (unsigned short*)alloc((size_t)256 * 256 * 2);
    unsigned short* Bt2       = (unsigned short*)alloc((size_t)96 * 256 * 2);
    (void)ws_size; (void)n_in; (void)in_sizes; (void)out_size;

    const int nscan = (NN + 1023) / 1024;

    hipMemsetAsync(deg, 0, (size_t)NN * 4, stream);
    count_deg_k<<<(NE + 255) / 256, 256, 0, stream>>>(dst, deg);
    scan_block_k<<<nscan, 1024, 0, stream>>>(deg, row_start, bsum);
    scan_bsum_k<<<1, 128, 0, stream>>>(bsum, nscan);
    scan_add_k<<<nscan, 1024, 0, stream>>>(row_start, row_pos, inv_deg, deg, bsum);
    fill_csr_k<<<(NE + 255) / 256, 256, 0, stream>>>(src, dst, row_pos, csr_src);

    cast_x_k<<<(NN * NF / 4 + 255) / 256, 256, 0, stream>>>(x, xb);
    prep_bt1_k<<<(256 * 256 + 255) / 256, 256, 0, stream>>>(Wl1, Wr1, Bt1);
    prep_bt2_k<<<(96 * 256 + 255) / 256, 256, 0, stream>>>(Wl2, Wr2, Bt2);

    agg_mean_128b_k<<<NN / 4, 256, 0, stream>>>(xb, csr_src, row_start, deg, inv_deg, mean1);

    gemm1_mfma_k<<<dim3((NN + 127) / 128, 2), 256, 0, stream>>>(mean1, xb, Bt1, b1, hbuf);
    gemm2_mfma_k<<<(NN + 127) / 128, 256, 0, stream>>>(hbuf, Bt2, b2, t, out);

    agg_mean_47_add_k<<<NN / 4, 256, 0, stream>>>(t, csr_src, row_start, deg, inv_deg, out);
}

// Round 3
// 464.171 us; speedup vs baseline: 1.7047x; 1.3251x over previous
//
#include <hip/hip_runtime.h>

#define NN 100000
#define NE 1600000
#define NF 128
#define NH 256
#define NC 47

typedef __attribute__((ext_vector_type(8))) short bf16x8;
typedef __attribute__((ext_vector_type(4))) float f32x4;

__device__ inline unsigned short f2bf(float f) {
    unsigned u = __builtin_bit_cast(unsigned, f);
    unsigned r = u + 0x7fffu + ((u >> 16) & 1u);
    return (unsigned short)(r >> 16);
}
__device__ inline float bfl(unsigned u) {           // low ushort -> float
    return __builtin_bit_cast(float, u << 16);
}
__device__ inline float bfh(unsigned u) {           // high ushort -> float
    return __builtin_bit_cast(float, u & 0xffff0000u);
}

// ---------------- CSR build ----------------

__global__ void count_deg_k(const int* __restrict__ dst, int* __restrict__ deg) {
    int e = blockIdx.x * blockDim.x + threadIdx.x;
    if (e < NE) atomicAdd(&deg[dst[e]], 1);
}

__global__ __launch_bounds__(1024) void scan_block_k(const int* __restrict__ deg,
                                                     int* __restrict__ row_start,
                                                     int* __restrict__ bsum) {
    __shared__ int s[1024];
    int tid = threadIdx.x;
    int i = blockIdx.x * 1024 + tid;
    int v = (i < NN) ? deg[i] : 0;
    s[tid] = v;
    __syncthreads();
    for (int off = 1; off < 1024; off <<= 1) {
        int t = (tid >= off) ? s[tid - off] : 0;
        __syncthreads();
        s[tid] += t;
        __syncthreads();
    }
    if (i < NN) row_start[i] = s[tid] - v;
    if (tid == 1023) bsum[blockIdx.x] = s[1023];
}

__global__ void scan_bsum_k(int* __restrict__ bsum, int nb) {
    __shared__ int s[128];
    int tid = threadIdx.x;
    int v = (tid < nb) ? bsum[tid] : 0;
    s[tid] = v;
    __syncthreads();
    for (int off = 1; off < 128; off <<= 1) {
        int t = (tid >= off) ? s[tid - off] : 0;
        __syncthreads();
        s[tid] += t;
        __syncthreads();
    }
    if (tid < nb) bsum[tid] = s[tid] - v;
}

__global__ __launch_bounds__(1024) void scan_add_k(int* __restrict__ row_start,
                                                   int* __restrict__ row_pos,
                                                   float* __restrict__ inv_deg,
                                                   const int* __restrict__ deg,
                                                   const int* __restrict__ bsum) {
    int i = blockIdx.x * 1024 + threadIdx.x;
    if (i < NN) {
        int rs = row_start[i] + bsum[blockIdx.x];
        row_start[i] = rs;
        row_pos[i] = rs;
        int d = deg[i];
        inv_deg[i] = 1.0f / (float)(d > 1 ? d : 1);
    }
}

__global__ void fill_csr_k(const int* __restrict__ src, const int* __restrict__ dst,
                           int* __restrict__ row_pos, int* __restrict__ csr_src) {
    int e = blockIdx.x * blockDim.x + threadIdx.x;
    if (e < NE) {
        int p = atomicAdd(&row_pos[dst[e]], 1);
        csr_src[p] = src[e];
    }
}

// ---------------- dtype prep ----------------

__global__ void cast_x_k(const float* __restrict__ x, unsigned short* __restrict__ xb) {
    int i = blockIdx.x * 256 + threadIdx.x;        // 4 floats per thread
    if (i >= NN * NF / 4) return;
    float4 v = *reinterpret_cast<const float4*>(x + (size_t)i * 4);
    ushort4 o;
    o.x = f2bf(v.x); o.y = f2bf(v.y); o.z = f2bf(v.z); o.w = f2bf(v.w);
    *reinterpret_cast<ushort4*>(xb + (size_t)i * 4) = o;
}

// Bt1[n][k], n<256, k<256: k<128 -> Wl1[k][n], else Wr1[k-128][n]
__global__ void prep_bt1_k(const float* __restrict__ Wl1, const float* __restrict__ Wr1,
                           unsigned short* __restrict__ Bt1) {
    int idx = blockIdx.x * 256 + threadIdx.x;
    if (idx >= 256 * 256) return;
    int n = idx >> 8, k = idx & 255;
    float v = (k < 128) ? Wl1[(size_t)k * NH + n] : Wr1[(size_t)(k - 128) * NH + n];
    Bt1[idx] = f2bf(v);
}

// Bt2[n][k], n<96, k<256: n<47 -> Wl2[k][n]; 48<=n<95 -> Wr2[k][n-48]; else 0
__global__ void prep_bt2_k(const float* __restrict__ Wl2, const float* __restrict__ Wr2,
                           unsigned short* __restrict__ Bt2) {
    int idx = blockIdx.x * 256 + threadIdx.x;
    if (idx >= 96 * 256) return;
    int n = idx >> 8, k = idx & 255;
    float v = 0.f;
    if (n < 47) v = Wl2[(size_t)k * NC + n];
    else if (n >= 48 && n < 95) v = Wr2[(size_t)k * NC + (n - 48)];
    Bt2[idx] = f2bf(v);
}

// ---------------- aggregation ----------------

// mean1[i,:] = inv_deg * sum_{j->i} xb[j,:]  (bf16 in, f32 acc, bf16 out), unroll 2
__global__ __launch_bounds__(256) void agg_mean_128b_k(const unsigned short* __restrict__ xb,
                                                       const int* __restrict__ csr_src,
                                                       const int* __restrict__ row_start,
                                                       const int* __restrict__ deg,
                                                       const float* __restrict__ inv_deg,
                                                       unsigned short* __restrict__ mean1) {
    int node = (blockIdx.x * 256 + threadIdx.x) >> 6;
    int lane = threadIdx.x & 63;
    if (node >= NN) return;
    int s0 = row_start[node];
    int d  = deg[node];
    float ax = 0.f, ay = 0.f;
    int j = 0;
    for (; j + 1 < d; j += 2) {
        int sA = csr_src[s0 + j];
        int sB = csr_src[s0 + j + 1];
        unsigned uA = *reinterpret_cast<const unsigned*>(xb + (size_t)sA * NF + lane * 2);
        unsigned uB = *reinterpret_cast<const unsigned*>(xb + (size_t)sB * NF + lane * 2);
        ax += bfl(uA); ay += bfh(uA);
        ax += bfl(uB); ay += bfh(uB);
    }
    if (j < d) {
        int s = csr_src[s0 + j];
        unsigned u = *reinterpret_cast<const unsigned*>(xb + (size_t)s * NF + lane * 2);
        ax += bfl(u); ay += bfh(u);
    }
    float inv = inv_deg[node];
    unsigned o = (unsigned)f2bf(ax * inv) | ((unsigned)f2bf(ay * inv) << 16);
    *reinterpret_cast<unsigned*>(mean1 + (size_t)node * NF + lane * 2) = o;
}

// out[i,c] += inv_deg * sum_{j->i} tb[j,c]   (bf16 rows padded to 64 = one 128B line), unroll 4
__global__ __launch_bounds__(256) void agg_mean_47b_add_k(const unsigned short* __restrict__ tb,
                                                          const int* __restrict__ csr_src,
                                                          const int* __restrict__ row_start,
                                                          const int* __restrict__ deg,
                                                          const float* __restrict__ inv_deg,
                                                          float* __restrict__ out) {
    int node = (blockIdx.x * 256 + threadIdx.x) >> 6;
    int lane = threadIdx.x & 63;
    if (node >= NN) return;
    int s0 = row_start[node];
    int d  = deg[node];
    float acc = 0.f;
    int j = 0;
    for (; j + 3 < d; j += 4) {
        int sA = csr_src[s0 + j];
        int sB = csr_src[s0 + j + 1];
        int sC = csr_src[s0 + j + 2];
        int sD = csr_src[s0 + j + 3];
        float a = bfl((unsigned)tb[(size_t)sA * 64 + lane]);
        float b = bfl((unsigned)tb[(size_t)sB * 64 + lane]);
        float c = bfl((unsigned)tb[(size_t)sC * 64 + lane]);
        float e = bfl((unsigned)tb[(size_t)sD * 64 + lane]);
        acc += a + b + c + e;
    }
    for (; j < d; ++j) {
        int s = csr_src[s0 + j];
        acc += bfl((unsigned)tb[(size_t)s * 64 + lane]);
    }
    if (lane < NC) {
        size_t o = (size_t)node * NC + lane;
        out[o] = out[o] + acc * inv_deg[node];
    }
}

// ---------------- GEMM1 (MFMA): h = relu([mean1|x]_bf16 @ Bt1^T + b1) ----------------

__global__ __launch_bounds__(256) void gemm1_mfma_k(const unsigned short* __restrict__ mean1,
                                                    const unsigned short* __restrict__ xb,
                                                    const unsigned short* __restrict__ Bt1,
                                                    const float* __restrict__ b1,
                                                    unsigned short* __restrict__ h) {
    __shared__ short As[2][128 * 32];
    __shared__ short Bs[2][128 * 32];
    const int tid = threadIdx.x;
    const int row0 = blockIdx.x * 128;
    const int col0 = blockIdx.y * 128;
    const int lane = tid & 63;
    const int wid = tid >> 6;
    const int wr = wid >> 1, wc = wid & 1;
    const int r15 = lane & 15;
    const int swz = ((lane >> 4) ^ ((lane >> 1) & 3)) & 3;

    f32x4 acc[4][4];
    #pragma unroll
    for (int i = 0; i < 4; ++i)
        #pragma unroll
        for (int j = 0; j < 4; ++j)
            acc[i][j] = f32x4{0.f, 0.f, 0.f, 0.f};

    bf16x8 ra[2], rb[2];

    auto load_tiles = [&](int kt) {
        #pragma unroll
        for (int i = 0; i < 2; ++i) {
            int c = tid + i * 256;
            int row = c >> 2, g = c & 3;
            int grow = row0 + row;
            const unsigned short* asrc = (kt < 128) ? mean1 : xb;
            int kb = (kt & 127) + g * 8;
            bf16x8 va = {0,0,0,0,0,0,0,0};
            if (grow < NN) va = *reinterpret_cast<const bf16x8*>(asrc + (size_t)grow * NF + kb);
            ra[i] = va;
            int n = col0 + row;
            rb[i] = *reinterpret_cast<const bf16x8*>(Bt1 + (size_t)n * 256 + kt + g * 8);
        }
    };
    auto write_tiles = [&](int buf) {
        #pragma unroll
        for (int i = 0; i < 2; ++i) {
            int c = tid + i * 256;
            int row = c >> 2, g = c & 3;
            int slot = g ^ ((row >> 1) & 3);
            *reinterpret_cast<bf16x8*>(&As[buf][row * 32 + slot * 8]) = ra[i];
            *reinterpret_cast<bf16x8*>(&Bs[buf][row * 32 + slot * 8]) = rb[i];
        }
    };
    auto compute = [&](int buf) {
        bf16x8 a[4], b[4];
        #pragma unroll
        for (int mi = 0; mi < 4; ++mi)
            a[mi] = *reinterpret_cast<const bf16x8*>(&As[buf][(wr * 64 + mi * 16 + r15) * 32 + swz * 8]);
        #pragma unroll
        for (int ni = 0; ni < 4; ++ni)
            b[ni] = *reinterpret_cast<const bf16x8*>(&Bs[buf][(wc * 64 + ni * 16 + r15) * 32 + swz * 8]);
        #pragma unroll
        for (int mi = 0; mi < 4; ++mi)
            #pragma unroll
            for (int ni = 0; ni < 4; ++ni)
                acc[mi][ni] = __builtin_amdgcn_mfma_f32_16x16x32_bf16(a[mi], b[ni], acc[mi][ni], 0, 0, 0);
    };

    load_tiles(0);
    write_tiles(0);
    __syncthreads();
    int cur = 0;
    #pragma unroll 1
    for (int ks = 0; ks < 8; ++ks) {
        if (ks + 1 < 8) load_tiles((ks + 1) * 32);
        compute(cur);
        if (ks + 1 < 8) write_tiles(cur ^ 1);
        __syncthreads();
        cur ^= 1;
    }

    #pragma unroll
    for (int ni = 0; ni < 4; ++ni) {
        int col = col0 + wc * 64 + ni * 16 + r15;
        float bias = b1[col];
        #pragma unroll
        for (int mi = 0; mi < 4; ++mi) {
            int rbase = row0 + wr * 64 + mi * 16 + (lane >> 4) * 4;
            f32x4 c = acc[mi][ni];
            #pragma unroll
            for (int q = 0; q < 4; ++q) {
                int row = rbase + q;
                if (row < NN) {
                    float v = fmaxf(c[q] + bias, 0.f);
                    h[(size_t)row * NH + col] = f2bf(v);
                }
            }
        }
    }
}

// ---------------- GEMM2 (MFMA): tb = bf16(h@Wl2) ; out = h@Wr2 + b2 ----------------

__global__ __launch_bounds__(256) void gemm2_mfma_k(const unsigned short* __restrict__ h,
                                                    const unsigned short* __restrict__ Bt2,
                                                    const float* __restrict__ b2,
                                                    unsigned short* __restrict__ tb,
                                                    float* __restrict__ out) {
    __shared__ short As[2][128 * 32];
    __shared__ short Bs[2][96 * 32];
    const int tid = threadIdx.x;
    const int row0 = blockIdx.x * 128;
    const int lane = tid & 63;
    const int wid = tid >> 6;
    const int wr = wid >> 1, wc = wid & 1;
    const int r15 = lane & 15;
    const int swz = ((lane >> 4) ^ ((lane >> 1) & 3)) & 3;

    f32x4 acc[4][3];
    #pragma unroll
    for (int i = 0; i < 4; ++i)
        #pragma unroll
        for (int j = 0; j < 3; ++j)
            acc[i][j] = f32x4{0.f, 0.f, 0.f, 0.f};

    bf16x8 ra[2], rb[2];

    auto load_tiles = [&](int kt) {
        #pragma unroll
        for (int i = 0; i < 2; ++i) {
            int c = tid + i * 256;
            int row = c >> 2, g = c & 3;
            int grow = row0 + row;
            bf16x8 va = {0,0,0,0,0,0,0,0};
            if (grow < NN) va = *reinterpret_cast<const bf16x8*>(h + (size_t)grow * NH + kt + g * 8);
            ra[i] = va;
            if (c < 96 * 4)
                rb[i] = *reinterpret_cast<const bf16x8*>(Bt2 + (size_t)row * 256 + kt + g * 8);
        }
    };
    auto write_tiles = [&](int buf) {
        #pragma unroll
        for (int i = 0; i < 2; ++i) {
            int c = tid + i * 256;
            int row = c >> 2, g = c & 3;
            int slot = g ^ ((row >> 1) & 3);
            *reinterpret_cast<bf16x8*>(&As[buf][row * 32 + slot * 8]) = ra[i];
            if (c < 96 * 4)
                *reinterpret_cast<bf16x8*>(&Bs[buf][row * 32 + slot * 8]) = rb[i];
        }
    };
    auto compute = [&](int buf) {
        bf16x8 a[4], b[3];
        #pragma unroll
        for (int mi = 0; mi < 4; ++mi)
            a[mi] = *reinterpret_cast<const bf16x8*>(&As[buf][(wr * 64 + mi * 16 + r15) * 32 + swz * 8]);
        #pragma unroll
        for (int ni = 0; ni < 3; ++ni)
            b[ni] = *reinterpret_cast<const bf16x8*>(&Bs[buf][(wc * 48 + ni * 16 + r15) * 32 + swz * 8]);
        #pragma unroll
        for (int mi = 0; mi < 4; ++mi)
            #pragma unroll
            for (int ni = 0; ni < 3; ++ni)
                acc[mi][ni] = __builtin_amdgcn_mfma_f32_16x16x32_bf16(a[mi], b[ni], acc[mi][ni], 0, 0, 0);
    };

    load_tiles(0);
    write_tiles(0);
    __syncthreads();
    int cur = 0;
    #pragma unroll 1
    for (int ks = 0; ks < 8; ++ks) {
        if (ks + 1 < 8) load_tiles((ks + 1) * 32);
        compute(cur);
        if (ks + 1 < 8) write_tiles(cur ^ 1);
        __syncthreads();
        cur ^= 1;
    }

    #pragma unroll
    for (int ni = 0; ni < 3; ++ni) {
        int col = wc * 48 + ni * 16 + r15;       // 0..95
        float bias = (col >= 48 && col < 95) ? b2[col - 48] : 0.f;
        #pragma unroll
        for (int mi = 0; mi < 4; ++mi) {
            int rbase = row0 + wr * 64 + mi * 16 + (lane >> 4) * 4;
            f32x4 c = acc[mi][ni];
            #pragma unroll
            for (int q = 0; q < 4; ++q) {
                int row = rbase + q;
                if (row < NN) {
                    if (col < 47)
                        tb[(size_t)row * 64 + col] = f2bf(c[q]);
                    else if (col >= 48 && col < 95)
                        out[(size_t)row * NC + (col - 48)] = c[q] + bias;
                }
            }
        }
    }
}

// ---------------- launch ----------------

extern "C" void kernel_launch(void* const* d_in, const int* in_sizes, int n_in,
                              void* d_out, int out_size, void* d_ws, size_t ws_size,
                              hipStream_t stream) {
    const float* x    = (const float*)d_in[0];
    const int*   eidx = (const int*)d_in[1];
    const float* Wl1  = (const float*)d_in[2];
    const float* Wr1  = (const float*)d_in[3];
    const float* b1   = (const float*)d_in[4];
    const float* Wl2  = (const float*)d_in[5];
    const float* Wr2  = (const float*)d_in[6];
    const float* b2   = (const float*)d_in[7];
    float* out = (float*)d_out;

    const int* src = eidx;
    const int* dst = eidx + NE;

    size_t off = 0;
    auto alloc = [&](size_t bytes) -> void* {
        void* p = (char*)d_ws + off;
        off += (bytes + 511) & ~(size_t)511;
        return p;
    };
    int*            deg       = (int*)alloc((size_t)NN * 4);
    int*            row_start = (int*)alloc((size_t)(NN + 1) * 4);
    int*            row_pos   = (int*)alloc((size_t)NN * 4);
    int*            bsum      = (int*)alloc(128 * 4);
    int*            csr_src   = (int*)alloc((size_t)NE * 4);
    float*          inv_deg   = (float*)alloc((size_t)NN * 4);
    unsigned short* xb        = (unsigned short*)alloc((size_t)NN * NF * 2);
    unsigned short* mean1     = (unsigned short*)alloc((size_t)NN * NF * 2);
    unsigned short* hbuf      = (unsigned short*)alloc((size_t)NN * NH * 2);
    unsigned short* tb        = (unsigned short*)alloc((size_t)NN * 64 * 2);  // 128B-aligned rows
    unsigned short* Bt1       = (unsigned short*)alloc((size_t)256 * 256 * 2);
    unsigned short* Bt2       = (unsigned short*)alloc((size_t)96 * 256 * 2);
    (void)ws_size; (void)n_in; (void)in_sizes; (void)out_size;

    const int nscan = (NN + 1023) / 1024;

    hipMemsetAsync(deg, 0, (size_t)NN * 4, stream);
    count_deg_k<<<(NE + 255) / 256, 256, 0, stream>>>(dst, deg);
    scan_block_k<<<nscan, 1024, 0, stream>>>(deg, row_start, bsum);
    scan_bsum_k<<<1, 128, 0, stream>>>(bsum, nscan);
    scan_add_k<<<nscan, 1024, 0, stream>>>(row_start, row_pos, inv_deg, deg, bsum);
    fill_csr_k<<<(NE + 255) / 256, 256, 0, stream>>>(src, dst, row_pos, csr_src);

    cast_x_k<<<(NN * NF / 4 + 255) / 256, 256, 0, stream>>>(x, xb);
    prep_bt1_k<<<(256 * 256 + 255) / 256, 256, 0, stream>>>(Wl1, Wr1, Bt1);
    prep_bt2_k<<<(96 * 256 + 255) / 256, 256, 0, stream>>>(Wl2, Wr2, Bt2);

    agg_mean_128b_k<<<NN / 4, 256, 0, stream>>>(xb, csr_src, row_start, deg, inv_deg, mean1);

    gemm1_mfma_k<<<dim3((NN + 127) / 128, 2), 256, 0, stream>>>(mean1, xb, Bt1, b1, hbuf);
    gemm2_mfma_k<<<(NN + 127) / 128, 256, 0, stream>>>(hbuf, Bt2, b2, tb, out);

    agg_mean_47b_add_k<<<NN / 4, 256, 0, stream>>>(tb, csr_src, row_start, deg, inv_deg, out);
}